// Round 1
// baseline (256.150 us; speedup 1.0000x reference)
//
#include <hip/hip_runtime.h>
#include <hip/hip_bf16.h>
#include <cstdint>

// Problem constants
// B=8 T=4 N1=1024 N2=64 DIM=1024 HEADS=8 DHEAD=64 INNER=512
// BT = 32, NR = N1+N2 = 1088, total concat rows = 34816
// Pipeline: transpose weights -> LN(concat) -> kv GEMM -> q GEMM -> attention -> out GEMM

typedef __bf16 bf16x8 __attribute__((ext_vector_type(8)));
typedef __bf16 bf16x4 __attribute__((ext_vector_type(4)));
typedef float  f32x4  __attribute__((ext_vector_type(4)));

// ---------------------------------------------------------------- transpose
// src: f32 [K][N] row-major  ->  dst: bf16 [N][K]
__global__ void transpose_cast(const float* __restrict__ src, __bf16* __restrict__ dst,
                               int K, int N) {
    __shared__ float tile[32][33];
    int n0 = blockIdx.x * 32, k0 = blockIdx.y * 32;
    int tx = threadIdx.x, ty = threadIdx.y;   // (32,8)
#pragma unroll
    for (int i = 0; i < 4; ++i)
        tile[ty + i * 8][tx] = src[(size_t)(k0 + ty + i * 8) * N + n0 + tx];
    __syncthreads();
#pragma unroll
    for (int i = 0; i < 4; ++i)
        dst[(size_t)(n0 + ty + i * 8) * K + k0 + tx] = (__bf16)tile[tx][ty + i * 8];
}

// ---------------------------------------------------------------- layernorm
// One block per row (1024 f32). Rows 0..1023 of each bt chunk are x, 1024..1087 latents.
__global__ __launch_bounds__(256) void ln_concat_kernel(
    const float* __restrict__ x, const float* __restrict__ lat,
    const float* __restrict__ g_m, const float* __restrict__ b_m,
    const float* __restrict__ g_l, const float* __restrict__ b_l,
    __bf16* __restrict__ out) {
    int row = blockIdx.x;               // 0..34815
    int bt  = row / 1088;
    int r   = row - bt * 1088;
    const float *src, *g, *b;
    if (r < 1024) { src = x   + ((size_t)(bt * 1024 + r) << 10);        g = g_m; b = b_m; }
    else          { src = lat + ((size_t)(bt * 64 + (r - 1024)) << 10); g = g_l; b = b_l; }
    int t = threadIdx.x;
    float4 v = ((const float4*)src)[t];
    float s = v.x + v.y + v.z + v.w;
    float q = v.x * v.x + v.y * v.y + v.z * v.z + v.w * v.w;
#pragma unroll
    for (int m = 1; m < 64; m <<= 1) { s += __shfl_xor(s, m); q += __shfl_xor(q, m); }
    __shared__ float ss[4], qq[4];
    int w = t >> 6;
    if ((t & 63) == 0) { ss[w] = s; qq[w] = q; }
    __syncthreads();
    s = ss[0] + ss[1] + ss[2] + ss[3];
    q = qq[0] + qq[1] + qq[2] + qq[3];
    float mean = s * (1.0f / 1024.0f);
    float var  = q * (1.0f / 1024.0f) - mean * mean;
    float rstd = rsqrtf(var + 1e-5f);
    float4 gv = ((const float4*)g)[t];
    float4 bv = ((const float4*)b)[t];
    bf16x4 o;
    o[0] = (__bf16)((v.x - mean) * rstd * gv.x + bv.x);
    o[1] = (__bf16)((v.y - mean) * rstd * gv.y + bv.y);
    o[2] = (__bf16)((v.z - mean) * rstd * gv.z + bv.z);
    o[3] = (__bf16)((v.w - mean) * rstd * gv.w + bv.w);
    *(bf16x4*)(out + ((size_t)row << 10) + t * 4) = o;
}

// ---------------------------------------------------------------- GEMM
// C[M][N] = A[M][K] @ Bt[N][K]^T, bf16 in, f32 acc, bf16 or f32 out.
// 128x128 tile, BK=64, 256 threads (4 waves, each 64x64 = 4x4 frags of 16x16x32).
// AMODE 0: A rows contiguous (lda=K). AMODE 1: A row gr maps to concat row
//          bt*1088 + 1024 + (gr&63), bt = gr>>6 (latent rows for q GEMM).
#define BM 128
#define BN 128
#define BKK 64

template <int AMODE, bool OUT_BF16>
__global__ __launch_bounds__(256) void gemm_bf16(
    const __bf16* __restrict__ A, const __bf16* __restrict__ Bt,
    void* __restrict__ C, int M, int N, int K, float scale) {
    __shared__ __bf16 Asw[BM * BKK];   // 16 KB, XOR-swizzled rows of 128B
    __shared__ __bf16 Bsw[BN * BKK];   // 16 KB
    int tid  = threadIdx.x;
    int lane = tid & 63, wave = tid >> 6;
    int bn = blockIdx.x, bm = blockIdx.y;
    int wr = (wave >> 1) * 64, wc = (wave & 1) * 64;
    int l15 = lane & 15, lh = lane >> 4;

    f32x4 acc[4][4] = {};

    for (int k0 = 0; k0 < K; k0 += BKK) {
        __syncthreads();
        // stage: 1024 chunks of 16B per tile; 4 per thread
#pragma unroll
        for (int it = 0; it < 4; ++it) {
            int idx = it * 256 + tid;
            int r = idx >> 3, c = idx & 7;      // row 0..127, 8-bf16 chunk 0..7
            const __bf16* ap;
            if (AMODE == 0) {
                ap = A + (size_t)(bm * BM + r) * K;
            } else {
                int gr = bm * BM + r;
                ap = A + (size_t)((gr >> 6) * 1088 + 1024 + (gr & 63)) * K;
            }
            uint4 da = *(const uint4*)(ap + k0 + c * 8);
            *(uint4*)((char*)Asw + r * 128 + ((c * 16) ^ ((r & 7) << 4))) = da;
            const __bf16* bp = Bt + (size_t)(bn * BN + r) * K;
            uint4 db = *(const uint4*)(bp + k0 + c * 8);
            *(uint4*)((char*)Bsw + r * 128 + ((c * 16) ^ ((r & 7) << 4))) = db;
        }
        __syncthreads();
#pragma unroll
        for (int kk = 0; kk < BKK; kk += 32) {
            int cb = (kk + lh * 8) * 2;   // byte offset of this lane's 16B chunk
            bf16x8 af[4], bfr[4];
#pragma unroll
            for (int mi = 0; mi < 4; ++mi) {
                int r = wr + mi * 16 + l15;
                af[mi] = *(const bf16x8*)((const char*)Asw + r * 128 + (cb ^ ((r & 7) << 4)));
            }
#pragma unroll
            for (int ni = 0; ni < 4; ++ni) {
                int r = wc + ni * 16 + l15;
                bfr[ni] = *(const bf16x8*)((const char*)Bsw + r * 128 + (cb ^ ((r & 7) << 4)));
            }
#pragma unroll
            for (int mi = 0; mi < 4; ++mi)
#pragma unroll
                for (int ni = 0; ni < 4; ++ni)
                    acc[mi][ni] = __builtin_amdgcn_mfma_f32_16x16x32_bf16(
                        af[mi], bfr[ni], acc[mi][ni], 0, 0, 0);
        }
    }
    // epilogue: D row = lh*4+jj, col = l15 (m89-verified layout)
#pragma unroll
    for (int mi = 0; mi < 4; ++mi)
#pragma unroll
        for (int ni = 0; ni < 4; ++ni)
#pragma unroll
            for (int jj = 0; jj < 4; ++jj) {
                int row = bm * BM + wr + mi * 16 + lh * 4 + jj;
                int col = bn * BN + wc + ni * 16 + l15;
                float val = acc[mi][ni][jj] * scale;
                if (OUT_BF16) ((__bf16*)C)[(size_t)row * N + col] = (__bf16)val;
                else          ((float*)C)[(size_t)row * N + col]  = val;
            }
}

// ---------------------------------------------------------------- attention
// One block per (bt, head): q [64][64], k/v [1088][64]. 4 waves x 16 q-rows.
// Online softmax; sim via mfma(q, k-rows); P relayout via per-wave swizzled LDS;
// V staged transposed (swizzled) so PV B-frags are contiguous ds_read_b128.
__global__ __launch_bounds__(256) void attn_kernel(
    const __bf16* __restrict__ q,    // [32][64][512], pre-scaled by 0.125
    const __bf16* __restrict__ kv,   // [32][1088][1024]  (k cols 0..511, v cols 512..1023)
    __bf16* __restrict__ o) {        // [32][64][512]
    int blk = blockIdx.x;            // 0..255
    int bt = blk >> 3, h = blk & 7;
    int tid = threadIdx.x, lane = tid & 63, wave = tid >> 6;
    int l15 = lane & 15, lh = lane >> 4;

    __shared__ __bf16 vT[64 * 64];        // [d][j], swizzled, 8 KB
    __shared__ __bf16 Pl[4][16 * 64];     // per-wave [r][j], swizzled, 8 KB

    const __bf16* qbase = q + ((size_t)bt * 64 + wave * 16) * 512 + h * 64;
    bf16x8 qf[2];
    qf[0] = *(const bf16x8*)(qbase + (size_t)l15 * 512 + lh * 8);
    qf[1] = *(const bf16x8*)(qbase + (size_t)l15 * 512 + 32 + lh * 8);

    const __bf16* kvbt = kv + (size_t)bt * 1088 * 1024;

    float m_s[4], l_s[4];
    f32x4 oacc[4];
#pragma unroll
    for (int jj = 0; jj < 4; ++jj) { m_s[jj] = -1e30f; l_s[jj] = 0.f; }
#pragma unroll
    for (int d = 0; d < 4; ++d) oacc[d] = f32x4{0.f, 0.f, 0.f, 0.f};

    for (int tile = 0; tile < 17; ++tile) {
        int j0 = tile * 64;
        __syncthreads();
        // stage vT[d][j] (swizzled): 2 iters x 256 threads x 8 elems
#pragma unroll
        for (int it = 0; it < 2; ++it) {
            int idx = it * 256 + tid;
            int j = idx >> 3, c = idx & 7;
            bf16x8 vv = *(const bf16x8*)(kvbt + (size_t)(j0 + j) * 1024 + 512 + h * 64 + c * 8);
#pragma unroll
            for (int e = 0; e < 8; ++e) {
                int d = c * 8 + e;
                *(__bf16*)((char*)vT + d * 128 + ((j * 2) ^ ((d & 7) << 4))) = vv[e];
            }
        }
        __syncthreads();

        // sim tile: 16 q-rows x 64 cols
        f32x4 s[4];
        f32x4 zero = {0.f, 0.f, 0.f, 0.f};
#pragma unroll
        for (int ni = 0; ni < 4; ++ni) {
            const __bf16* kp = kvbt + (size_t)(j0 + ni * 16 + l15) * 1024 + h * 64;
            bf16x8 kf0 = *(const bf16x8*)(kp + lh * 8);
            bf16x8 kf1 = *(const bf16x8*)(kp + 32 + lh * 8);
            f32x4 t0 = __builtin_amdgcn_mfma_f32_16x16x32_bf16(qf[0], kf0, zero, 0, 0, 0);
            s[ni]    = __builtin_amdgcn_mfma_f32_16x16x32_bf16(qf[1], kf1, t0,   0, 0, 0);
        }

        // online softmax (rows = lh*4+jj)
        float tm[4];
#pragma unroll
        for (int jj = 0; jj < 4; ++jj)
            tm[jj] = fmaxf(fmaxf(s[0][jj], s[1][jj]), fmaxf(s[2][jj], s[3][jj]));
#pragma unroll
        for (int m = 1; m < 16; m <<= 1)
#pragma unroll
            for (int jj = 0; jj < 4; ++jj) tm[jj] = fmaxf(tm[jj], __shfl_xor(tm[jj], m));

        float alpha[4];
#pragma unroll
        for (int jj = 0; jj < 4; ++jj) {
            float mn = fmaxf(m_s[jj], tm[jj]);
            alpha[jj] = __expf(m_s[jj] - mn);
            m_s[jj] = mn;
        }
        float p[4][4];
        float ts[4] = {0.f, 0.f, 0.f, 0.f};
#pragma unroll
        for (int ni = 0; ni < 4; ++ni)
#pragma unroll
            for (int jj = 0; jj < 4; ++jj) {
                p[ni][jj] = __expf(s[ni][jj] - m_s[jj]);
                ts[jj] += p[ni][jj];
            }
#pragma unroll
        for (int m = 1; m < 16; m <<= 1)
#pragma unroll
            for (int jj = 0; jj < 4; ++jj) ts[jj] += __shfl_xor(ts[jj], m);
#pragma unroll
        for (int jj = 0; jj < 4; ++jj) l_s[jj] = l_s[jj] * alpha[jj] + ts[jj];
#pragma unroll
        for (int d = 0; d < 4; ++d)
#pragma unroll
            for (int jj = 0; jj < 4; ++jj) oacc[d][jj] *= alpha[jj];

        // write P (bf16) to per-wave swizzled LDS: row r = lh*4+jj, col j = ni*16+l15
#pragma unroll
        for (int ni = 0; ni < 4; ++ni)
#pragma unroll
            for (int jj = 0; jj < 4; ++jj) {
                int r = lh * 4 + jj, j = ni * 16 + l15;
                *(__bf16*)((char*)Pl[wave] + r * 128 + ((j * 2) ^ ((r & 7) << 4))) =
                    (__bf16)p[ni][jj];
            }
        __syncthreads();   // P write -> P read (cross-lane), also orders vT reuse

        // PV: A = P rows (r=l15), B = vT
        bf16x8 pf[2];
        pf[0] = *(const bf16x8*)((char*)Pl[wave] + l15 * 128 + ((lh * 16)      ^ ((l15 & 7) << 4)));
        pf[1] = *(const bf16x8*)((char*)Pl[wave] + l15 * 128 + ((64 + lh * 16) ^ ((l15 & 7) << 4)));
#pragma unroll
        for (int dblk = 0; dblk < 4; ++dblk) {
            int dr = dblk * 16 + l15;
            bf16x8 vf0 = *(const bf16x8*)((char*)vT + dr * 128 + ((lh * 16)      ^ ((dr & 7) << 4)));
            bf16x8 vf1 = *(const bf16x8*)((char*)vT + dr * 128 + ((64 + lh * 16) ^ ((dr & 7) << 4)));
            oacc[dblk] = __builtin_amdgcn_mfma_f32_16x16x32_bf16(pf[0], vf0, oacc[dblk], 0, 0, 0);
            oacc[dblk] = __builtin_amdgcn_mfma_f32_16x16x32_bf16(pf[1], vf1, oacc[dblk], 0, 0, 0);
        }
    }

    // normalize + write [bt][64][512]
    __bf16* ob = o + ((size_t)bt * 64 + wave * 16) * 512 + h * 64;
#pragma unroll
    for (int dblk = 0; dblk < 4; ++dblk)
#pragma unroll
        for (int jj = 0; jj < 4; ++jj) {
            int r = lh * 4 + jj;
            ob[(size_t)r * 512 + dblk * 16 + l15] = (__bf16)(oacc[dblk][jj] / l_s[jj]);
        }
}

// ---------------------------------------------------------------- launch
extern "C" void kernel_launch(void* const* d_in, const int* in_sizes, int n_in,
                              void* d_out, int out_size, void* d_ws, size_t ws_size,
                              hipStream_t stream) {
    const float* x    = (const float*)d_in[0];
    const float* lat  = (const float*)d_in[1];
    const float* g_m  = (const float*)d_in[2];
    const float* b_m  = (const float*)d_in[3];
    const float* g_l  = (const float*)d_in[4];
    const float* b_l  = (const float*)d_in[5];
    const float* Wq   = (const float*)d_in[6];
    const float* Wkv  = (const float*)d_in[7];
    const float* Wout = (const float*)d_in[8];
    float* out = (float*)d_out;

    char* ws = (char*)d_ws;
    __bf16* concat = (__bf16*)ws; ws += (size_t)34816 * 1024 * 2;   // LN(x)||LN(lat), bf16
    __bf16* kvb    = (__bf16*)ws; ws += (size_t)34816 * 1024 * 2;   // kv
    __bf16* qb     = (__bf16*)ws; ws += (size_t)2048 * 512 * 2;     // q (pre-scaled)
    __bf16* ab     = (__bf16*)ws; ws += (size_t)2048 * 512 * 2;     // attn out
    __bf16* WqT    = (__bf16*)ws; ws += (size_t)512 * 1024 * 2;
    __bf16* WkvT   = (__bf16*)ws; ws += (size_t)1024 * 1024 * 2;
    __bf16* WoutT  = (__bf16*)ws; ws += (size_t)1024 * 512 * 2;

    transpose_cast<<<dim3(512 / 32, 1024 / 32), dim3(32, 8), 0, stream>>>(Wq,   WqT,   1024, 512);
    transpose_cast<<<dim3(1024 / 32, 1024 / 32), dim3(32, 8), 0, stream>>>(Wkv, WkvT,  1024, 1024);
    transpose_cast<<<dim3(1024 / 32, 512 / 32), dim3(32, 8), 0, stream>>>(Wout, WoutT, 512, 1024);

    ln_concat_kernel<<<34816, 256, 0, stream>>>(x, lat, g_m, b_m, g_l, b_l, concat);

    // kv = concat @ Wkv   (M=34816, N=1024, K=1024)
    gemm_bf16<0, true><<<dim3(1024 / BN, 34816 / BM), 256, 0, stream>>>(
        concat, WkvT, kvb, 34816, 1024, 1024, 1.0f);
    // q = LN(lat) @ Wq * 0.125   (M=2048, N=512, K=1024), latent rows of concat
    gemm_bf16<1, true><<<dim3(512 / BN, 2048 / BM), 256, 0, stream>>>(
        concat, WqT, qb, 2048, 512, 1024, 0.125f);

    attn_kernel<<<256, 256, 0, stream>>>(qb, kvb, ab);

    // out = attn @ Wout   (M=2048, N=1024, K=512), f32 output
    gemm_bf16<0, false><<<dim3(1024 / BN, 2048 / BM), 256, 0, stream>>>(
        ab, WoutT, out, 2048, 1024, 512, 1.0f);
}

// Round 2
// 249.028 us; speedup vs baseline: 1.0286x; 1.0286x over previous
//
#include <hip/hip_runtime.h>
#include <hip/hip_bf16.h>
#include <cstdint>

// B=8 T=4 N1=1024 N2=64 DIM=1024 HEADS=8 DHEAD=64 INNER=512
// BT = 32, NR = N1+N2 = 1088, concat rows = 34816
// Pipeline: transpose weights -> LN(concat) -> kv GEMM -> q GEMM -> attention -> out GEMM

typedef __bf16 bf16x8 __attribute__((ext_vector_type(8)));
typedef __bf16 bf16x4 __attribute__((ext_vector_type(4)));
typedef float  f32x4  __attribute__((ext_vector_type(4)));

__device__ __forceinline__ void gload_lds16(const void* g, void* l) {
    __builtin_amdgcn_global_load_lds(
        (const __attribute__((address_space(1))) unsigned int*)g,
        (__attribute__((address_space(3))) unsigned int*)l, 16, 0, 0);
}

// ---------------------------------------------------------------- transpose
__global__ void transpose_cast(const float* __restrict__ src, __bf16* __restrict__ dst,
                               int K, int N) {
    __shared__ float tile[32][33];
    int n0 = blockIdx.x * 32, k0 = blockIdx.y * 32;
    int tx = threadIdx.x, ty = threadIdx.y;   // (32,8)
#pragma unroll
    for (int i = 0; i < 4; ++i)
        tile[ty + i * 8][tx] = src[(size_t)(k0 + ty + i * 8) * N + n0 + tx];
    __syncthreads();
#pragma unroll
    for (int i = 0; i < 4; ++i)
        dst[(size_t)(n0 + ty + i * 8) * K + k0 + tx] = (__bf16)tile[tx][ty + i * 8];
}

// ---------------------------------------------------------------- layernorm
__global__ __launch_bounds__(256) void ln_concat_kernel(
    const float* __restrict__ x, const float* __restrict__ lat,
    const float* __restrict__ g_m, const float* __restrict__ b_m,
    const float* __restrict__ g_l, const float* __restrict__ b_l,
    __bf16* __restrict__ out) {
    int row = blockIdx.x;               // 0..34815
    int bt  = row / 1088;
    int r   = row - bt * 1088;
    const float *src, *g, *b;
    if (r < 1024) { src = x   + ((size_t)(bt * 1024 + r) << 10);        g = g_m; b = b_m; }
    else          { src = lat + ((size_t)(bt * 64 + (r - 1024)) << 10); g = g_l; b = b_l; }
    int t = threadIdx.x;
    float4 v = ((const float4*)src)[t];
    float s = v.x + v.y + v.z + v.w;
    float q = v.x * v.x + v.y * v.y + v.z * v.z + v.w * v.w;
#pragma unroll
    for (int m = 1; m < 64; m <<= 1) { s += __shfl_xor(s, m); q += __shfl_xor(q, m); }
    __shared__ float ss[4], qq[4];
    int w = t >> 6;
    if ((t & 63) == 0) { ss[w] = s; qq[w] = q; }
    __syncthreads();
    s = ss[0] + ss[1] + ss[2] + ss[3];
    q = qq[0] + qq[1] + qq[2] + qq[3];
    float mean = s * (1.0f / 1024.0f);
    float var  = q * (1.0f / 1024.0f) - mean * mean;
    float rstd = rsqrtf(var + 1e-5f);
    float4 gv = ((const float4*)g)[t];
    float4 bv = ((const float4*)b)[t];
    bf16x4 o;
    o[0] = (__bf16)((v.x - mean) * rstd * gv.x + bv.x);
    o[1] = (__bf16)((v.y - mean) * rstd * gv.y + bv.y);
    o[2] = (__bf16)((v.z - mean) * rstd * gv.z + bv.z);
    o[3] = (__bf16)((v.w - mean) * rstd * gv.w + bv.w);
    *(bf16x4*)(out + ((size_t)row << 10) + t * 4) = o;
}

// ---------------------------------------------------------------- GEMM (m97 structure)
// C[M][N] = A[M][K] @ Bt[N][K]^T. 128x128 tile, BK=64, 256 threads (4 waves).
// global_load_lds width=16 staging, LINEAR LDS [row][64], 1-D grid + XCD swizzle.
#define BM 128
#define BN 128
#define BKK 64

template <int AMODE, bool OUT_BF16>
__global__ __launch_bounds__(256) void gemm_bf16(
    const __bf16* __restrict__ A, const __bf16* __restrict__ Bt,
    void* __restrict__ C, int M, int N, int K, float scale, int gx) {
    __shared__ __bf16 As[BM * BKK];   // 16 KB linear
    __shared__ __bf16 Bs[BN * BKK];   // 16 KB linear
    int tid  = threadIdx.x;
    int lane = tid & 63, wave = tid >> 6;

    // XCD-aware swizzle: physical id -> logical tile; nwg % 8 == 0 by construction
    int nwg = gridDim.x;
    int id  = blockIdx.x;
    int cpx = nwg >> 3;
    int swz = (id & 7) * cpx + (id >> 3);
    int bm = swz / gx, bn = swz % gx;

    int wr = (wave >> 1) * 64, wc = (wave & 1) * 64;
    int l15 = lane & 15, lh = lane >> 4;
    int srow = lane >> 3;             // row within 8-row issue
    int scol = (lane & 7) * 8;        // bf16 elem offset within 64

    // per-lane global base pointers (k0 = 0)
    const __bf16* abase[4];
    const __bf16* bbase[4];
#pragma unroll
    for (int i = 0; i < 4; ++i) {
        int r = wave * 32 + i * 8 + srow;
        if (AMODE == 0) {
            abase[i] = A + (size_t)(bm * BM + r) * K + scol;
        } else {
            int gr = bm * BM + r;
            abase[i] = A + (size_t)((gr >> 6) * 1088 + 1024 + (gr & 63)) * K + scol;
        }
        bbase[i] = Bt + (size_t)(bn * BN + r) * K + scol;
    }

    f32x4 acc[4][4] = {};

    for (int k0 = 0; k0 < K; k0 += BKK) {
        __syncthreads();   // prior reads of As/Bs complete
#pragma unroll
        for (int i = 0; i < 4; ++i) {
            gload_lds16(abase[i] + k0, &As[(wave * 32 + i * 8) * BKK]);
            gload_lds16(bbase[i] + k0, &Bs[(wave * 32 + i * 8) * BKK]);
        }
        __syncthreads();   // drains vmcnt(0): tile resident
#pragma unroll
        for (int kk = 0; kk < BKK; kk += 32) {
            bf16x8 af[4], bfr[4];
#pragma unroll
            for (int mi = 0; mi < 4; ++mi)
                af[mi] = *(const bf16x8*)&As[(wr + mi * 16 + l15) * BKK + kk + lh * 8];
#pragma unroll
            for (int ni = 0; ni < 4; ++ni)
                bfr[ni] = *(const bf16x8*)&Bs[(wc + ni * 16 + l15) * BKK + kk + lh * 8];
#pragma unroll
            for (int mi = 0; mi < 4; ++mi)
#pragma unroll
                for (int ni = 0; ni < 4; ++ni)
                    acc[mi][ni] = __builtin_amdgcn_mfma_f32_16x16x32_bf16(
                        af[mi], bfr[ni], acc[mi][ni], 0, 0, 0);
        }
    }
    // epilogue: D row = lh*4+jj, col = l15 (m89-verified)
#pragma unroll
    for (int mi = 0; mi < 4; ++mi)
#pragma unroll
        for (int ni = 0; ni < 4; ++ni)
#pragma unroll
            for (int jj = 0; jj < 4; ++jj) {
                int row = bm * BM + wr + mi * 16 + lh * 4 + jj;
                int col = bn * BN + wc + ni * 16 + l15;
                float val = acc[mi][ni][jj] * scale;
                if (OUT_BF16) ((__bf16*)C)[(size_t)row * N + col] = (__bf16)val;
                else          ((float*)C)[(size_t)row * N + col]  = val;
            }
}

// ---------------------------------------------------------------- attention
// One block per (bt, head), 1024 threads = 4 KV-chunks x 4 q-row-waves (16 waves, 4/SIMD).
// Each chunk runs online softmax over tiles cid, cid+4, ... ; flash merge at the end.
__global__ __launch_bounds__(1024) void attn_kernel(
    const __bf16* __restrict__ q,    // [32][64][512], pre-scaled by 0.125
    const __bf16* __restrict__ kv,   // [32][1088][1024]  (k: cols 0..511, v: 512..1023)
    __bf16* __restrict__ o) {        // [32][64][512]
    int blk = blockIdx.x;            // 0..255
    int bt = blk >> 3, h = blk & 7;
    int tid = threadIdx.x;
    int cid  = tid >> 8;             // KV chunk 0..3
    int ctid = tid & 255;
    int wave = tid >> 6;             // 0..15
    int g    = wave & 3;             // q-row group (rows g*16..g*16+15)
    int lane = tid & 63, l15 = lane & 15, lh = lane >> 4;

    __shared__ __bf16 vT[4][64 * 64];     // per-chunk [d][j] swizzled, 32 KB
    __shared__ __bf16 Pl[16][16 * 64];    // per-wave  [r][j] swizzled, 32 KB
    // aliases (regions dead at time of use):
    float* mbuf = (float*)&vT[1][0];      // [4][4][16]
    float* lbuf = mbuf + 256;             // [4][4][16]
    float* Osum = (float*)&Pl[0][0];      // [4][16][64]

    const __bf16* qbase = q + ((size_t)bt * 64 + g * 16) * 512 + h * 64;
    bf16x8 qf[2];
    qf[0] = *(const bf16x8*)(qbase + (size_t)l15 * 512 + lh * 8);
    qf[1] = *(const bf16x8*)(qbase + (size_t)l15 * 512 + 32 + lh * 8);

    const __bf16* kvbt = kv + (size_t)bt * 1088 * 1024;

    float m_s[4], l_s[4];
    f32x4 oacc[4];
#pragma unroll
    for (int jj = 0; jj < 4; ++jj) { m_s[jj] = -1e30f; l_s[jj] = 0.f; }
#pragma unroll
    for (int d = 0; d < 4; ++d) oacc[d] = f32x4{0.f, 0.f, 0.f, 0.f};

    for (int it = 0; it < 5; ++it) {
        int tile = it * 4 + cid;
        bool act = tile < 17;
        int j0 = tile * 64;
        __syncthreads();
        if (act) {
            // stage vT[cid][d][j] (swizzled): 2 x 256 threads x 8 elems
#pragma unroll
            for (int it2 = 0; it2 < 2; ++it2) {
                int idx = it2 * 256 + ctid;
                int j = idx >> 3, c = idx & 7;
                bf16x8 vv = *(const bf16x8*)(kvbt + (size_t)(j0 + j) * 1024 + 512 + h * 64 + c * 8);
#pragma unroll
                for (int e = 0; e < 8; ++e) {
                    int d = c * 8 + e;
                    *(__bf16*)((char*)vT[cid] + d * 128 + ((j * 2) ^ ((d & 7) << 4))) = vv[e];
                }
            }
        }
        __syncthreads();
        if (act) {
            // sim tile: 16 q-rows x 64 cols
            f32x4 s[4];
            f32x4 zero = {0.f, 0.f, 0.f, 0.f};
#pragma unroll
            for (int ni = 0; ni < 4; ++ni) {
                const __bf16* kp = kvbt + (size_t)(j0 + ni * 16 + l15) * 1024 + h * 64;
                bf16x8 kf0 = *(const bf16x8*)(kp + lh * 8);
                bf16x8 kf1 = *(const bf16x8*)(kp + 32 + lh * 8);
                f32x4 t0 = __builtin_amdgcn_mfma_f32_16x16x32_bf16(qf[0], kf0, zero, 0, 0, 0);
                s[ni]    = __builtin_amdgcn_mfma_f32_16x16x32_bf16(qf[1], kf1, t0,   0, 0, 0);
            }
            // online softmax (rows = lh*4+jj)
            float tm[4];
#pragma unroll
            for (int jj = 0; jj < 4; ++jj)
                tm[jj] = fmaxf(fmaxf(s[0][jj], s[1][jj]), fmaxf(s[2][jj], s[3][jj]));
#pragma unroll
            for (int m = 1; m < 16; m <<= 1)
#pragma unroll
                for (int jj = 0; jj < 4; ++jj) tm[jj] = fmaxf(tm[jj], __shfl_xor(tm[jj], m));
            float alpha[4];
#pragma unroll
            for (int jj = 0; jj < 4; ++jj) {
                float mn = fmaxf(m_s[jj], tm[jj]);
                alpha[jj] = __expf(m_s[jj] - mn);
                m_s[jj] = mn;
            }
            float p[4][4];
            float ts[4] = {0.f, 0.f, 0.f, 0.f};
#pragma unroll
            for (int ni = 0; ni < 4; ++ni)
#pragma unroll
                for (int jj = 0; jj < 4; ++jj) {
                    p[ni][jj] = __expf(s[ni][jj] - m_s[jj]);
                    ts[jj] += p[ni][jj];
                }
#pragma unroll
            for (int m = 1; m < 16; m <<= 1)
#pragma unroll
                for (int jj = 0; jj < 4; ++jj) ts[jj] += __shfl_xor(ts[jj], m);
#pragma unroll
            for (int jj = 0; jj < 4; ++jj) l_s[jj] = l_s[jj] * alpha[jj] + ts[jj];
#pragma unroll
            for (int d = 0; d < 4; ++d)
#pragma unroll
                for (int jj = 0; jj < 4; ++jj) oacc[d][jj] *= alpha[jj];
            // write P (bf16): row r = lh*4+jj, col j = ni*16+l15
#pragma unroll
            for (int ni = 0; ni < 4; ++ni)
#pragma unroll
                for (int jj = 0; jj < 4; ++jj) {
                    int r = lh * 4 + jj, j = ni * 16 + l15;
                    *(__bf16*)((char*)Pl[wave] + r * 128 + ((j * 2) ^ ((r & 7) << 4))) =
                        (__bf16)p[ni][jj];
                }
        }
        __syncthreads();   // P write -> P read
        if (act) {
            bf16x8 pf[2];
            pf[0] = *(const bf16x8*)((char*)Pl[wave] + l15 * 128 + ((lh * 16)      ^ ((l15 & 7) << 4)));
            pf[1] = *(const bf16x8*)((char*)Pl[wave] + l15 * 128 + ((64 + lh * 16) ^ ((l15 & 7) << 4)));
#pragma unroll
            for (int dblk = 0; dblk < 4; ++dblk) {
                int dr = dblk * 16 + l15;
                bf16x8 vf0 = *(const bf16x8*)((char*)vT[cid] + dr * 128 + ((lh * 16)      ^ ((dr & 7) << 4)));
                bf16x8 vf1 = *(const bf16x8*)((char*)vT[cid] + dr * 128 + ((64 + lh * 16) ^ ((dr & 7) << 4)));
                oacc[dblk] = __builtin_amdgcn_mfma_f32_16x16x32_bf16(pf[0], vf0, oacc[dblk], 0, 0, 0);
                oacc[dblk] = __builtin_amdgcn_mfma_f32_16x16x32_bf16(pf[1], vf1, oacc[dblk], 0, 0, 0);
            }
        }
    }

    // -------- flash merge of 4 chunk-partials --------
    __syncthreads();
    if (l15 == 0) {
#pragma unroll
        for (int jj = 0; jj < 4; ++jj) {
            mbuf[(cid * 4 + g) * 16 + lh * 4 + jj] = m_s[jj];
            lbuf[(cid * 4 + g) * 16 + lh * 4 + jj] = l_s[jj];
        }
    }
    __syncthreads();
    float sc[4], Lsum[4];
#pragma unroll
    for (int jj = 0; jj < 4; ++jj) {
        int r = lh * 4 + jj;
        float M = mbuf[(0 * 4 + g) * 16 + r];
#pragma unroll
        for (int c = 1; c < 4; ++c) M = fmaxf(M, mbuf[(c * 4 + g) * 16 + r]);
        sc[jj] = __expf(m_s[jj] - M);
        float L = 0.f;
#pragma unroll
        for (int c = 0; c < 4; ++c)
            L += lbuf[(c * 4 + g) * 16 + r] * __expf(mbuf[(c * 4 + g) * 16 + r] - M);
        Lsum[jj] = L;
    }
#pragma unroll
    for (int c = 0; c < 4; ++c) {
        if (cid == c) {
#pragma unroll
            for (int dblk = 0; dblk < 4; ++dblk)
#pragma unroll
                for (int jj = 0; jj < 4; ++jj) {
                    int off = (g * 16 + lh * 4 + jj) * 64 + dblk * 16 + l15;
                    float v = oacc[dblk][jj] * sc[jj];
                    if (c == 0) Osum[off] = v;
                    else        Osum[off] += v;
                }
        }
        __syncthreads();
    }
    if (cid == 0) {
        __bf16* ob = o + ((size_t)bt * 64 + g * 16) * 512 + h * 64;
#pragma unroll
        for (int dblk = 0; dblk < 4; ++dblk)
#pragma unroll
            for (int jj = 0; jj < 4; ++jj) {
                int r = lh * 4 + jj;
                float v = Osum[(g * 16 + r) * 64 + dblk * 16 + l15] / Lsum[jj];
                ob[(size_t)r * 512 + dblk * 16 + l15] = (__bf16)v;
            }
    }
}

// ---------------------------------------------------------------- launch
extern "C" void kernel_launch(void* const* d_in, const int* in_sizes, int n_in,
                              void* d_out, int out_size, void* d_ws, size_t ws_size,
                              hipStream_t stream) {
    const float* x    = (const float*)d_in[0];
    const float* lat  = (const float*)d_in[1];
    const float* g_m  = (const float*)d_in[2];
    const float* b_m  = (const float*)d_in[3];
    const float* g_l  = (const float*)d_in[4];
    const float* b_l  = (const float*)d_in[5];
    const float* Wq   = (const float*)d_in[6];
    const float* Wkv  = (const float*)d_in[7];
    const float* Wout = (const float*)d_in[8];
    float* out = (float*)d_out;

    char* ws = (char*)d_ws;
    __bf16* concat = (__bf16*)ws; ws += (size_t)34816 * 1024 * 2;
    __bf16* kvb    = (__bf16*)ws; ws += (size_t)34816 * 1024 * 2;
    __bf16* qb     = (__bf16*)ws; ws += (size_t)2048 * 512 * 2;
    __bf16* ab     = (__bf16*)ws; ws += (size_t)2048 * 512 * 2;
    __bf16* WqT    = (__bf16*)ws; ws += (size_t)512 * 1024 * 2;
    __bf16* WkvT   = (__bf16*)ws; ws += (size_t)1024 * 1024 * 2;
    __bf16* WoutT  = (__bf16*)ws; ws += (size_t)1024 * 512 * 2;

    transpose_cast<<<dim3(512 / 32, 1024 / 32), dim3(32, 8), 0, stream>>>(Wq,   WqT,   1024, 512);
    transpose_cast<<<dim3(1024 / 32, 1024 / 32), dim3(32, 8), 0, stream>>>(Wkv, WkvT,  1024, 1024);
    transpose_cast<<<dim3(1024 / 32, 512 / 32), dim3(32, 8), 0, stream>>>(Wout, WoutT, 512, 1024);

    ln_concat_kernel<<<34816, 256, 0, stream>>>(x, lat, g_m, b_m, g_l, b_l, concat);

    // kv = concat @ Wkv   (M=34816, N=1024, K=1024); nwg = 272*8 = 2176
    gemm_bf16<0, true><<<2176, 256, 0, stream>>>(concat, WkvT, kvb, 34816, 1024, 1024, 1.0f, 8);
    // q = LN(lat) @ Wq * 0.125   (M=2048, N=512, K=1024); nwg = 16*4 = 64
    gemm_bf16<1, true><<<64, 256, 0, stream>>>(concat, WqT, qb, 2048, 512, 1024, 0.125f, 4);

    attn_kernel<<<256, 1024, 0, stream>>>(qb, kvb, ab);

    // out = attn @ Wout   (M=2048, N=1024, K=512); nwg = 16*8 = 128
    gemm_bf16<0, false><<<128, 256, 0, stream>>>(ab, WoutT, out, 2048, 1024, 512, 1.0f, 8);
}

// Round 3
// 212.833 us; speedup vs baseline: 1.2035x; 1.1701x over previous
//
#include <hip/hip_runtime.h>
#include <hip/hip_bf16.h>
#include <cstdint>

// B=8 T=4 N1=1024 N2=64 DIM=1024 HEADS=8 DHEAD=64 INNER=512
// BT = 32, NR = N1+N2 = 1088, concat rows = 34816
// Pipeline: transpose weights -> LN(concat) -> kv GEMM -> q GEMM -> attention -> out GEMM

typedef __bf16 bf16x8 __attribute__((ext_vector_type(8)));
typedef __bf16 bf16x4 __attribute__((ext_vector_type(4)));
typedef float  f32x4  __attribute__((ext_vector_type(4)));

__device__ __forceinline__ void gload_lds16(const void* g, void* l) {
    __builtin_amdgcn_global_load_lds(
        (const __attribute__((address_space(1))) unsigned int*)g,
        (__attribute__((address_space(3))) unsigned int*)l, 16, 0, 0);
}

// ---------------------------------------------------------------- transpose
__global__ void transpose_cast(const float* __restrict__ src, __bf16* __restrict__ dst,
                               int K, int N) {
    __shared__ float tile[32][33];
    int n0 = blockIdx.x * 32, k0 = blockIdx.y * 32;
    int tx = threadIdx.x, ty = threadIdx.y;   // (32,8)
#pragma unroll
    for (int i = 0; i < 4; ++i)
        tile[ty + i * 8][tx] = src[(size_t)(k0 + ty + i * 8) * N + n0 + tx];
    __syncthreads();
#pragma unroll
    for (int i = 0; i < 4; ++i)
        dst[(size_t)(n0 + ty + i * 8) * K + k0 + tx] = (__bf16)tile[tx][ty + i * 8];
}

// ---------------------------------------------------------------- layernorm
__global__ __launch_bounds__(256) void ln_concat_kernel(
    const float* __restrict__ x, const float* __restrict__ lat,
    const float* __restrict__ g_m, const float* __restrict__ b_m,
    const float* __restrict__ g_l, const float* __restrict__ b_l,
    __bf16* __restrict__ out) {
    int row = blockIdx.x;               // 0..34815
    int bt  = row / 1088;
    int r   = row - bt * 1088;
    const float *src, *g, *b;
    if (r < 1024) { src = x   + ((size_t)(bt * 1024 + r) << 10);        g = g_m; b = b_m; }
    else          { src = lat + ((size_t)(bt * 64 + (r - 1024)) << 10); g = g_l; b = b_l; }
    int t = threadIdx.x;
    float4 v = ((const float4*)src)[t];
    float s = v.x + v.y + v.z + v.w;
    float q = v.x * v.x + v.y * v.y + v.z * v.z + v.w * v.w;
#pragma unroll
    for (int m = 1; m < 64; m <<= 1) { s += __shfl_xor(s, m); q += __shfl_xor(q, m); }
    __shared__ float ss[4], qq[4];
    int w = t >> 6;
    if ((t & 63) == 0) { ss[w] = s; qq[w] = q; }
    __syncthreads();
    s = ss[0] + ss[1] + ss[2] + ss[3];
    q = qq[0] + qq[1] + qq[2] + qq[3];
    float mean = s * (1.0f / 1024.0f);
    float var  = q * (1.0f / 1024.0f) - mean * mean;
    float rstd = rsqrtf(var + 1e-5f);
    float4 gv = ((const float4*)g)[t];
    float4 bv = ((const float4*)b)[t];
    bf16x4 o;
    o[0] = (__bf16)((v.x - mean) * rstd * gv.x + bv.x);
    o[1] = (__bf16)((v.y - mean) * rstd * gv.y + bv.y);
    o[2] = (__bf16)((v.z - mean) * rstd * gv.z + bv.z);
    o[3] = (__bf16)((v.w - mean) * rstd * gv.w + bv.w);
    *(bf16x4*)(out + ((size_t)row << 10) + t * 4) = o;
}

// ---------------------------------------------------------------- GEMM
// C[M][N] = A[M][K] @ Bt[N][K]^T. 128x128 tile, BK=64, 256 threads (4 waves).
// global_load_lds width=16 with INVERSE-SWIZZLED global source column (rule #21):
// lane (r=lane>>3, c=lane&7) fetches global chunk c^r so LDS holds the XOR-swizzled
// layout; fragment reads apply cb ^ ((row&7)<<4)  (round-1-verified conflict-free).
#define BM 128
#define BN 128
#define BKK 64

template <int AMODE, bool OUT_BF16>
__global__ __launch_bounds__(256) void gemm_bf16(
    const __bf16* __restrict__ A, const __bf16* __restrict__ Bt,
    void* __restrict__ C, int M, int N, int K, float scale, int gx) {
    __shared__ __bf16 As[BM * BKK];   // 16 KB, swizzled via source permutation
    __shared__ __bf16 Bs[BN * BKK];   // 16 KB
    int tid  = threadIdx.x;
    int lane = tid & 63, wave = tid >> 6;

    // XCD-aware swizzle: nwg % 8 == 0 by construction
    int nwg = gridDim.x;
    int id  = blockIdx.x;
    int cpx = nwg >> 3;
    int swz = (id & 7) * cpx + (id >> 3);
    int bm = swz / gx, bn = swz % gx;

    int wr = (wave >> 1) * 64, wc = (wave & 1) * 64;
    int l15 = lane & 15, lh = lane >> 4;
    int srow = lane >> 3;                         // row within 8-row issue (0..7)
    int scol = ((lane & 7) ^ srow) * 8;           // inverse-swizzled source column

    // per-lane global base pointers (k0 = 0)
    const __bf16* abase[4];
    const __bf16* bbase[4];
#pragma unroll
    for (int i = 0; i < 4; ++i) {
        int r = wave * 32 + i * 8 + srow;
        if (AMODE == 0) {
            abase[i] = A + (size_t)(bm * BM + r) * K + scol;
        } else {
            int gr = bm * BM + r;
            abase[i] = A + (size_t)((gr >> 6) * 1088 + 1024 + (gr & 63)) * K + scol;
        }
        bbase[i] = Bt + (size_t)(bn * BN + r) * K + scol;
    }

    f32x4 acc[4][4] = {};

    for (int k0 = 0; k0 < K; k0 += BKK) {
        __syncthreads();   // prior reads of As/Bs complete
#pragma unroll
        for (int i = 0; i < 4; ++i) {
            gload_lds16(abase[i] + k0, &As[(wave * 32 + i * 8) * BKK]);
            gload_lds16(bbase[i] + k0, &Bs[(wave * 32 + i * 8) * BKK]);
        }
        __syncthreads();   // drains vmcnt(0): tile resident
#pragma unroll
        for (int kk = 0; kk < BKK; kk += 32) {
            int cb = (kk + lh * 8) * 2;   // byte offset of this lane's 16B chunk
            bf16x8 af[4], bfr[4];
#pragma unroll
            for (int mi = 0; mi < 4; ++mi) {
                int r = wr + mi * 16 + l15;
                af[mi] = *(const bf16x8*)((const char*)As + r * 128 + (cb ^ ((r & 7) << 4)));
            }
#pragma unroll
            for (int ni = 0; ni < 4; ++ni) {
                int r = wc + ni * 16 + l15;
                bfr[ni] = *(const bf16x8*)((const char*)Bs + r * 128 + (cb ^ ((r & 7) << 4)));
            }
#pragma unroll
            for (int mi = 0; mi < 4; ++mi)
#pragma unroll
                for (int ni = 0; ni < 4; ++ni)
                    acc[mi][ni] = __builtin_amdgcn_mfma_f32_16x16x32_bf16(
                        af[mi], bfr[ni], acc[mi][ni], 0, 0, 0);
        }
    }
    // epilogue: D row = lh*4+jj, col = l15 (m89-verified)
#pragma unroll
    for (int mi = 0; mi < 4; ++mi)
#pragma unroll
        for (int ni = 0; ni < 4; ++ni)
#pragma unroll
            for (int jj = 0; jj < 4; ++jj) {
                int row = bm * BM + wr + mi * 16 + lh * 4 + jj;
                int col = bn * BN + wc + ni * 16 + l15;
                float val = acc[mi][ni][jj] * scale;
                if (OUT_BF16) ((__bf16*)C)[(size_t)row * N + col] = (__bf16)val;
                else          ((float*)C)[(size_t)row * N + col]  = val;
            }
}

// ---------------------------------------------------------------- attention
// One block per (bt, head), 1024 threads = 4 KV-chunks x 4 q-row-waves (16 waves, 4/SIMD).
__global__ __launch_bounds__(1024) void attn_kernel(
    const __bf16* __restrict__ q,    // [32][64][512], pre-scaled by 0.125
    const __bf16* __restrict__ kv,   // [32][1088][1024]  (k: cols 0..511, v: 512..1023)
    __bf16* __restrict__ o) {        // [32][64][512]
    int blk = blockIdx.x;            // 0..255
    int bt = blk >> 3, h = blk & 7;
    int tid = threadIdx.x;
    int cid  = tid >> 8;             // KV chunk 0..3
    int ctid = tid & 255;
    int wave = tid >> 6;             // 0..15
    int g    = wave & 3;             // q-row group (rows g*16..g*16+15)
    int lane = tid & 63, l15 = lane & 15, lh = lane >> 4;

    __shared__ __bf16 vT[4][64 * 64];     // per-chunk [d][j] swizzled, 32 KB
    __shared__ __bf16 Pl[16][16 * 64];    // per-wave  [r][j] swizzled, 32 KB
    float* mbuf = (float*)&vT[1][0];      // [4][4][16]  (aliased, dead region)
    float* lbuf = mbuf + 256;             // [4][4][16]
    float* Osum = (float*)&Pl[0][0];      // [4][16][64]

    const __bf16* qbase = q + ((size_t)bt * 64 + g * 16) * 512 + h * 64;
    bf16x8 qf[2];
    qf[0] = *(const bf16x8*)(qbase + (size_t)l15 * 512 + lh * 8);
    qf[1] = *(const bf16x8*)(qbase + (size_t)l15 * 512 + 32 + lh * 8);

    const __bf16* kvbt = kv + (size_t)bt * 1088 * 1024;

    float m_s[4], l_s[4];
    f32x4 oacc[4];
#pragma unroll
    for (int jj = 0; jj < 4; ++jj) { m_s[jj] = -1e30f; l_s[jj] = 0.f; }
#pragma unroll
    for (int d = 0; d < 4; ++d) oacc[d] = f32x4{0.f, 0.f, 0.f, 0.f};

    for (int it = 0; it < 5; ++it) {
        int tile = it * 4 + cid;
        bool act = tile < 17;
        int j0 = tile * 64;
        __syncthreads();
        if (act) {
#pragma unroll
            for (int it2 = 0; it2 < 2; ++it2) {
                int idx = it2 * 256 + ctid;
                int j = idx >> 3, c = idx & 7;
                bf16x8 vv = *(const bf16x8*)(kvbt + (size_t)(j0 + j) * 1024 + 512 + h * 64 + c * 8);
#pragma unroll
                for (int e = 0; e < 8; ++e) {
                    int d = c * 8 + e;
                    *(__bf16*)((char*)vT[cid] + d * 128 + ((j * 2) ^ ((d & 7) << 4))) = vv[e];
                }
            }
        }
        __syncthreads();
        if (act) {
            f32x4 s[4];
            f32x4 zero = {0.f, 0.f, 0.f, 0.f};
#pragma unroll
            for (int ni = 0; ni < 4; ++ni) {
                const __bf16* kp = kvbt + (size_t)(j0 + ni * 16 + l15) * 1024 + h * 64;
                bf16x8 kf0 = *(const bf16x8*)(kp + lh * 8);
                bf16x8 kf1 = *(const bf16x8*)(kp + 32 + lh * 8);
                f32x4 t0 = __builtin_amdgcn_mfma_f32_16x16x32_bf16(qf[0], kf0, zero, 0, 0, 0);
                s[ni]    = __builtin_amdgcn_mfma_f32_16x16x32_bf16(qf[1], kf1, t0,   0, 0, 0);
            }
            float tm[4];
#pragma unroll
            for (int jj = 0; jj < 4; ++jj)
                tm[jj] = fmaxf(fmaxf(s[0][jj], s[1][jj]), fmaxf(s[2][jj], s[3][jj]));
#pragma unroll
            for (int m = 1; m < 16; m <<= 1)
#pragma unroll
                for (int jj = 0; jj < 4; ++jj) tm[jj] = fmaxf(tm[jj], __shfl_xor(tm[jj], m));
            float alpha[4];
#pragma unroll
            for (int jj = 0; jj < 4; ++jj) {
                float mn = fmaxf(m_s[jj], tm[jj]);
                alpha[jj] = __expf(m_s[jj] - mn);
                m_s[jj] = mn;
            }
            float p[4][4];
            float ts[4] = {0.f, 0.f, 0.f, 0.f};
#pragma unroll
            for (int ni = 0; ni < 4; ++ni)
#pragma unroll
                for (int jj = 0; jj < 4; ++jj) {
                    p[ni][jj] = __expf(s[ni][jj] - m_s[jj]);
                    ts[jj] += p[ni][jj];
                }
#pragma unroll
            for (int m = 1; m < 16; m <<= 1)
#pragma unroll
                for (int jj = 0; jj < 4; ++jj) ts[jj] += __shfl_xor(ts[jj], m);
#pragma unroll
            for (int jj = 0; jj < 4; ++jj) l_s[jj] = l_s[jj] * alpha[jj] + ts[jj];
#pragma unroll
            for (int d = 0; d < 4; ++d)
#pragma unroll
                for (int jj = 0; jj < 4; ++jj) oacc[d][jj] *= alpha[jj];
#pragma unroll
            for (int ni = 0; ni < 4; ++ni)
#pragma unroll
                for (int jj = 0; jj < 4; ++jj) {
                    int r = lh * 4 + jj, j = ni * 16 + l15;
                    *(__bf16*)((char*)Pl[wave] + r * 128 + ((j * 2) ^ ((r & 7) << 4))) =
                        (__bf16)p[ni][jj];
                }
        }
        __syncthreads();   // P write -> P read
        if (act) {
            bf16x8 pf[2];
            pf[0] = *(const bf16x8*)((char*)Pl[wave] + l15 * 128 + ((lh * 16)      ^ ((l15 & 7) << 4)));
            pf[1] = *(const bf16x8*)((char*)Pl[wave] + l15 * 128 + ((64 + lh * 16) ^ ((l15 & 7) << 4)));
#pragma unroll
            for (int dblk = 0; dblk < 4; ++dblk) {
                int dr = dblk * 16 + l15;
                bf16x8 vf0 = *(const bf16x8*)((char*)vT[cid] + dr * 128 + ((lh * 16)      ^ ((dr & 7) << 4)));
                bf16x8 vf1 = *(const bf16x8*)((char*)vT[cid] + dr * 128 + ((64 + lh * 16) ^ ((dr & 7) << 4)));
                oacc[dblk] = __builtin_amdgcn_mfma_f32_16x16x32_bf16(pf[0], vf0, oacc[dblk], 0, 0, 0);
                oacc[dblk] = __builtin_amdgcn_mfma_f32_16x16x32_bf16(pf[1], vf1, oacc[dblk], 0, 0, 0);
            }
        }
    }

    // -------- flash merge of 4 chunk-partials --------
    __syncthreads();
    if (l15 == 0) {
#pragma unroll
        for (int jj = 0; jj < 4; ++jj) {
            mbuf[(cid * 4 + g) * 16 + lh * 4 + jj] = m_s[jj];
            lbuf[(cid * 4 + g) * 16 + lh * 4 + jj] = l_s[jj];
        }
    }
    __syncthreads();
    float sc[4], Lsum[4];
#pragma unroll
    for (int jj = 0; jj < 4; ++jj) {
        int r = lh * 4 + jj;
        float M = mbuf[(0 * 4 + g) * 16 + r];
#pragma unroll
        for (int c = 1; c < 4; ++c) M = fmaxf(M, mbuf[(c * 4 + g) * 16 + r]);
        sc[jj] = __expf(m_s[jj] - M);
        float L = 0.f;
#pragma unroll
        for (int c = 0; c < 4; ++c)
            L += lbuf[(c * 4 + g) * 16 + r] * __expf(mbuf[(c * 4 + g) * 16 + r] - M);
        Lsum[jj] = L;
    }
#pragma unroll
    for (int c = 0; c < 4; ++c) {
        if (cid == c) {
#pragma unroll
            for (int dblk = 0; dblk < 4; ++dblk)
#pragma unroll
                for (int jj = 0; jj < 4; ++jj) {
                    int off = (g * 16 + lh * 4 + jj) * 64 + dblk * 16 + l15;
                    float v = oacc[dblk][jj] * sc[jj];
                    if (c == 0) Osum[off] = v;
                    else        Osum[off] += v;
                }
        }
        __syncthreads();
    }
    if (cid == 0) {
        __bf16* ob = o + ((size_t)bt * 64 + g * 16) * 512 + h * 64;
#pragma unroll
        for (int dblk = 0; dblk < 4; ++dblk)
#pragma unroll
            for (int jj = 0; jj < 4; ++jj) {
                int r = lh * 4 + jj;
                float v = Osum[(g * 16 + r) * 64 + dblk * 16 + l15] / Lsum[jj];
                ob[(size_t)r * 512 + dblk * 16 + l15] = (__bf16)v;
            }
    }
}

// ---------------------------------------------------------------- launch
extern "C" void kernel_launch(void* const* d_in, const int* in_sizes, int n_in,
                              void* d_out, int out_size, void* d_ws, size_t ws_size,
                              hipStream_t stream) {
    const float* x    = (const float*)d_in[0];
    const float* lat  = (const float*)d_in[1];
    const float* g_m  = (const float*)d_in[2];
    const float* b_m  = (const float*)d_in[3];
    const float* g_l  = (const float*)d_in[4];
    const float* b_l  = (const float*)d_in[5];
    const float* Wq   = (const float*)d_in[6];
    const float* Wkv  = (const float*)d_in[7];
    const float* Wout = (const float*)d_in[8];
    float* out = (float*)d_out;

    char* ws = (char*)d_ws;
    __bf16* concat = (__bf16*)ws; ws += (size_t)34816 * 1024 * 2;
    __bf16* kvb    = (__bf16*)ws; ws += (size_t)34816 * 1024 * 2;
    __bf16* qb     = (__bf16*)ws; ws += (size_t)2048 * 512 * 2;
    __bf16* ab     = (__bf16*)ws; ws += (size_t)2048 * 512 * 2;
    __bf16* WqT    = (__bf16*)ws; ws += (size_t)512 * 1024 * 2;
    __bf16* WkvT   = (__bf16*)ws; ws += (size_t)1024 * 1024 * 2;
    __bf16* WoutT  = (__bf16*)ws; ws += (size_t)1024 * 512 * 2;

    transpose_cast<<<dim3(512 / 32, 1024 / 32), dim3(32, 8), 0, stream>>>(Wq,   WqT,   1024, 512);
    transpose_cast<<<dim3(1024 / 32, 1024 / 32), dim3(32, 8), 0, stream>>>(Wkv, WkvT,  1024, 1024);
    transpose_cast<<<dim3(1024 / 32, 512 / 32), dim3(32, 8), 0, stream>>>(Wout, WoutT, 512, 1024);

    ln_concat_kernel<<<34816, 256, 0, stream>>>(x, lat, g_m, b_m, g_l, b_l, concat);

    // kv = concat @ Wkv   (M=34816, N=1024, K=1024); nwg = 272*8 = 2176
    gemm_bf16<0, true><<<2176, 256, 0, stream>>>(concat, WkvT, kvb, 34816, 1024, 1024, 1.0f, 8);
    // q = LN(lat) @ Wq * 0.125   (M=2048, N=512, K=1024); nwg = 16*4 = 64
    gemm_bf16<1, true><<<64, 256, 0, stream>>>(concat, WqT, qb, 2048, 512, 1024, 0.125f, 4);

    attn_kernel<<<256, 1024, 0, stream>>>(qb, kvb, ab);

    // out = attn @ Wout   (M=2048, N=1024, K=512); nwg = 16*8 = 128
    gemm_bf16<0, false><<<128, 256, 0, stream>>>(ab, WoutT, out, 2048, 1024, 512, 1.0f, 8);
}